// Round 4
// baseline (1185.658 us; speedup 1.0000x reference)
//
#include <hip/hip_runtime.h>

#define N_NODES 25000
#define E_EDGES 400000
#define KM 200     // message channels
#define RS 224     // fused row stride (floats): 200 A/B + up to 20 x + pad (896B, line-aligned)

// ---------------- sort-by-dst (CSR build) ----------------

__global__ void hist_kernel(const int* __restrict__ edges, int* __restrict__ hist) {
  int e = blockIdx.x * blockDim.x + threadIdx.x;
  if (e < E_EDGES) atomicAdd(&hist[edges[E_EDGES + e]], 1);
}

__global__ void scan_kernel(const int* __restrict__ hist, int* __restrict__ off,
                            int* __restrict__ cursor) {
  __shared__ int sums[1024];
  const int CH = (N_NODES + 1023) / 1024;  // 25
  int tid = threadIdx.x;
  int base = tid * CH;
  int s = 0;
  for (int i = 0; i < CH; i++) {
    int idx = base + i;
    if (idx < N_NODES) s += hist[idx];
  }
  sums[tid] = s;
  __syncthreads();
  for (int d = 1; d < 1024; d <<= 1) {
    int v = (tid >= d) ? sums[tid - d] : 0;
    __syncthreads();
    sums[tid] += v;
    __syncthreads();
  }
  int run = (tid == 0) ? 0 : sums[tid - 1];
  for (int i = 0; i < CH; i++) {
    int idx = base + i;
    if (idx < N_NODES) {
      off[idx] = run;
      cursor[idx] = run;
      run += hist[idx];
    }
  }
  if (tid == 1023) off[N_NODES] = run;  // == E
}

__global__ void scatter_kernel(const int* __restrict__ edges, int* __restrict__ cursor,
                               int* __restrict__ srcS, int* __restrict__ dstS) {
  int e = blockIdx.x * blockDim.x + threadIdx.x;
  if (e < E_EDGES) {
    int s = edges[e];
    int d = edges[E_EDGES + e];
    int pos = atomicAdd(&cursor[d], 1);
    srcS[pos] = s;
    dstS[pos] = d;
  }
}

// ---------------- per-layer kernels ----------------

// Node prep: xv = relu?(xin)
//   A2[n] = [ xv@Wm1_top + bm1 (200) | xv (CIN) | pad ]   (stride RS floats)
//   B2[n] = [ xv@Wm1_bot       (200) | xv (CIN) | pad ]
//   xr[n][c] = xv  (compact copy for fin_kernel)
template <int CIN>
__global__ void prep_kernel(const float* __restrict__ xin, int do_relu,
                            const float* __restrict__ Wm1, const float* __restrict__ bm1,
                            float* __restrict__ A2, float* __restrict__ B2,
                            float* __restrict__ xr) {
  const int NT = 8;
  int k = threadIdx.x;  // 0..255
  float wa[CIN], wb[CIN];
  float bm = 0.f;
  if (k < KM) {
    bm = bm1[k];
#pragma unroll
    for (int c = 0; c < CIN; c++) {
      wa[c] = Wm1[c * KM + k];
      wb[c] = Wm1[(CIN + c) * KM + k];
    }
  }
  int n0 = blockIdx.x * NT;
  for (int i = 0; i < NT; i++) {
    int n = n0 + i;
    float xv[CIN];
#pragma unroll
    for (int c = 0; c < CIN; c++) {
      float v = xin[n * CIN + c];
      xv[c] = do_relu ? fmaxf(v, 0.f) : v;
    }
    size_t row = (size_t)n * RS;
    if (k < CIN) {
      xr[n * CIN + k] = xv[k];
      A2[row + KM + k] = xv[k];
      B2[row + KM + k] = xv[k];
    }
    if (k < KM) {
      float a = bm, b = 0.f;
#pragma unroll
      for (int c = 0; c < CIN; c++) {
        a += xv[c] * wa[c];
        b += xv[c] * wb[c];
      }
      A2[row + k] = a;
      B2[row + k] = b;
    }
  }
}

// Edge kernel: one thread per (dst-sorted) edge, aggregation fused.
// h_k = relu(A2[dst][k] + B2[src][k]); gate = h@Wm2 + bm2;
// msg[c] = gate[c]*(xi[c]-xj[c]); segmented wave-reduce over equal-dst runs;
// one atomicAdd per (run, c) into aggp[dst][c].
template <int CIN>
__global__ void __launch_bounds__(256) edge_kernel(
    const int* __restrict__ srcS, const int* __restrict__ dstS,
    const float* __restrict__ A2, const float* __restrict__ B2,
    const float* __restrict__ Wm2, const float* __restrict__ bm2,
    float* __restrict__ aggp) {
  int e0 = blockIdx.x * 256 + threadIdx.x;
  bool valid = (e0 < E_EDGES);
  int e = valid ? e0 : (E_EDGES - 1);
  int src = srcS[e];
  int dst = dstS[e];
  const float* Ar = A2 + (size_t)dst * RS;
  const float* Br = B2 + (size_t)src * RS;
  float gate[CIN];
#pragma unroll
  for (int c = 0; c < CIN; c++) gate[c] = bm2[c];

  // main k loop: 6 iters of 32 channels; 16 float4 loads hoisted per iter (MLP)
#pragma unroll 1
  for (int k0 = 0; k0 < 192; k0 += 32) {
    float4 a[8], b[8];
#pragma unroll
    for (int j = 0; j < 8; j++) {
      a[j] = *(const float4*)(Ar + k0 + 4 * j);
      b[j] = *(const float4*)(Br + k0 + 4 * j);
    }
#pragma unroll
    for (int j = 0; j < 8; j++) {
      float h0 = fmaxf(a[j].x + b[j].x, 0.f);
      float h1 = fmaxf(a[j].y + b[j].y, 0.f);
      float h2 = fmaxf(a[j].z + b[j].z, 0.f);
      float h3 = fmaxf(a[j].w + b[j].w, 0.f);
      int kb = k0 + 4 * j;
#pragma unroll
      for (int c = 0; c < CIN; c++) {
        gate[c] += h0 * Wm2[(kb + 0) * CIN + c] + h1 * Wm2[(kb + 1) * CIN + c] +
                   h2 * Wm2[(kb + 2) * CIN + c] + h3 * Wm2[(kb + 3) * CIN + c];
      }
    }
  }
  {  // tail k = 192..199
    float4 a[2], b[2];
#pragma unroll
    for (int j = 0; j < 2; j++) {
      a[j] = *(const float4*)(Ar + 192 + 4 * j);
      b[j] = *(const float4*)(Br + 192 + 4 * j);
    }
#pragma unroll
    for (int j = 0; j < 2; j++) {
      float h0 = fmaxf(a[j].x + b[j].x, 0.f);
      float h1 = fmaxf(a[j].y + b[j].y, 0.f);
      float h2 = fmaxf(a[j].z + b[j].z, 0.f);
      float h3 = fmaxf(a[j].w + b[j].w, 0.f);
      int kb = 192 + 4 * j;
#pragma unroll
      for (int c = 0; c < CIN; c++) {
        gate[c] += h0 * Wm2[(kb + 0) * CIN + c] + h1 * Wm2[(kb + 1) * CIN + c] +
                   h2 * Wm2[(kb + 2) * CIN + c] + h3 * Wm2[(kb + 3) * CIN + c];
      }
    }
  }

  // x-diff tails (same rows, L1-hot)
  float xd[CIN];
  if constexpr (CIN % 4 == 0) {
#pragma unroll
    for (int q = 0; q < CIN / 4; q++) {
      float4 xa = *(const float4*)(Ar + KM + 4 * q);
      float4 xb = *(const float4*)(Br + KM + 4 * q);
      xd[4 * q + 0] = xa.x - xb.x;
      xd[4 * q + 1] = xa.y - xb.y;
      xd[4 * q + 2] = xa.z - xb.z;
      xd[4 * q + 3] = xa.w - xb.w;
    }
  } else {
#pragma unroll
    for (int c = 0; c < CIN; c++) xd[c] = Ar[KM + c] - Br[KM + c];
  }

  // segmented reduction over equal-dst runs (dst-sorted => runs are contiguous)
  int lane = threadIdx.x & 63;
  bool seg[6];
#pragma unroll
  for (int i = 0; i < 6; i++) {
    int s = 1 << i;
    int od = __shfl_up(dst, s);
    seg[i] = (lane >= s) && (od == dst);
  }
  int dn = __shfl_down(dst, 1);
  bool is_last = (lane == 63) || (dn != dst);
  float* outp = aggp + (size_t)dst * CIN;
#pragma unroll
  for (int c = 0; c < CIN; c++) {
    float v = valid ? gate[c] * xd[c] : 0.f;
#pragma unroll
    for (int i = 0; i < 6; i++) {
      float o = __shfl_up(v, 1 << i);
      if (seg[i]) v += o;
    }
    if (is_last) atomicAdd(outp + c, v);
  }
}

// fin: thread per node: out[n][o] = aggp@W2 + deg*b2 + xr@W1 + b1
template <int CIN, int COUT>
__global__ void fin_kernel(const float* __restrict__ aggp, const int* __restrict__ off,
                           const float* __restrict__ xr,
                           const float* __restrict__ W1, const float* __restrict__ b1,
                           const float* __restrict__ W2, const float* __restrict__ b2,
                           float* __restrict__ out) {
  int n = blockIdx.x * blockDim.x + threadIdx.x;
  if (n >= N_NODES) return;
  float deg = (float)(off[n + 1] - off[n]);
  float ag[CIN], xv[CIN];
#pragma unroll
  for (int c = 0; c < CIN; c++) {
    ag[c] = aggp[(size_t)n * CIN + c];
    xv[c] = xr[(size_t)n * CIN + c];
  }
#pragma unroll
  for (int o = 0; o < COUT; o++) {
    float v = b1[o] + deg * b2[o];
#pragma unroll
    for (int c = 0; c < CIN; c++) v += ag[c] * W2[c * COUT + o] + xv[c] * W1[c * COUT + o];
    out[(size_t)n * COUT + o] = v;
  }
}

// ---------------- launch ----------------

extern "C" void kernel_launch(void* const* d_in, const int* in_sizes, int n_in,
                              void* d_out, int out_size, void* d_ws, size_t ws_size,
                              hipStream_t stream) {
  const float* features = (const float*)d_in[0];
  const int* edges = (const int*)d_in[1];
  // d_in[2] = weights (unused by reference)

  const float *dW1 = (const float*)d_in[3], *db1 = (const float*)d_in[4],
              *dWm1 = (const float*)d_in[5], *dbm1 = (const float*)d_in[6],
              *dWm2 = (const float*)d_in[7], *dbm2 = (const float*)d_in[8],
              *dW2 = (const float*)d_in[9], *db2 = (const float*)d_in[10];
  const float *hW1 = (const float*)d_in[11], *hb1 = (const float*)d_in[12],
              *hWm1 = (const float*)d_in[13], *hbm1 = (const float*)d_in[14],
              *hWm2 = (const float*)d_in[15], *hbm2 = (const float*)d_in[16],
              *hW2 = (const float*)d_in[17], *hb2 = (const float*)d_in[18];
  const float *oW1 = (const float*)d_in[19], *ob1 = (const float*)d_in[20],
              *oWm1 = (const float*)d_in[21], *obm1 = (const float*)d_in[22],
              *oWm2 = (const float*)d_in[23], *obm2 = (const float*)d_in[24],
              *oW2 = (const float*)d_in[25], *ob2 = (const float*)d_in[26];

  // workspace layout (float units)
  float* fws = (float*)d_ws;
  size_t o = 0;
  float* A2 = fws + o;   o += (size_t)N_NODES * RS;   // 5.6M
  float* B2 = fws + o;   o += (size_t)N_NODES * RS;   // 5.6M
  float* xr = fws + o;   o += (size_t)N_NODES * 20;
  float* aggp = fws + o; o += (size_t)N_NODES * 20;
  float* acc1 = fws + o; o += (size_t)N_NODES * 20;
  float* acc2 = fws + o; o += (size_t)N_NODES * 20;
  int* ip = (int*)(fws + o);
  int* hist = ip;   ip += N_NODES;
  int* off = ip;    ip += N_NODES + 4;
  int* cursor = ip; ip += N_NODES;
  int* srcS = ip;   ip += E_EDGES;
  int* dstS = ip;   ip += E_EDGES;

  const int B256 = 256;
  const int EDGE_G = (E_EDGES + B256 - 1) / B256;  // 1563
  const int NODE_G = (N_NODES + B256 - 1) / B256;
  const int PREP_G = N_NODES / 8;  // 3125, exact
  const size_t AGGP_BYTES = (size_t)N_NODES * 20 * sizeof(float);

  // build dst-sorted edge list + CSR offsets (recomputed every launch)
  hipMemsetAsync(hist, 0, N_NODES * sizeof(int), stream);
  hist_kernel<<<EDGE_G, B256, 0, stream>>>(edges, hist);
  scan_kernel<<<1, 1024, 0, stream>>>(hist, off, cursor);
  scatter_kernel<<<EDGE_G, B256, 0, stream>>>(edges, cursor, srcS, dstS);

  // layer d: 1 -> 20
  prep_kernel<1><<<PREP_G, B256, 0, stream>>>(features, 0, dWm1, dbm1, A2, B2, xr);
  hipMemsetAsync(aggp, 0, AGGP_BYTES, stream);
  edge_kernel<1><<<EDGE_G, B256, 0, stream>>>(srcS, dstS, A2, B2, dWm2, dbm2, aggp);
  fin_kernel<1, 20><<<NODE_G, B256, 0, stream>>>(aggp, off, xr, dW1, db1, dW2, db2, acc1);

  // 3 hidden layers: 20 -> 20 (relu applied to input inside prep)
  float* cur = acc1;
  float* nxt = acc2;
  for (int i = 0; i < 3; i++) {
    prep_kernel<20><<<PREP_G, B256, 0, stream>>>(cur, 1, hWm1, hbm1, A2, B2, xr);
    hipMemsetAsync(aggp, 0, AGGP_BYTES, stream);
    edge_kernel<20><<<EDGE_G, B256, 0, stream>>>(srcS, dstS, A2, B2, hWm2, hbm2, aggp);
    fin_kernel<20, 20><<<NODE_G, B256, 0, stream>>>(aggp, off, xr, hW1, hb1, hW2, hb2, nxt);
    float* tmp = cur; cur = nxt; nxt = tmp;
  }

  // output layer: 20 -> 1 (no trailing relu)
  prep_kernel<20><<<PREP_G, B256, 0, stream>>>(cur, 1, oWm1, obm1, A2, B2, xr);
  hipMemsetAsync(aggp, 0, AGGP_BYTES, stream);
  edge_kernel<20><<<EDGE_G, B256, 0, stream>>>(srcS, dstS, A2, B2, oWm2, obm2, aggp);
  fin_kernel<20, 1><<<NODE_G, B256, 0, stream>>>(aggp, off, xr, oW1, ob1, oW2, ob2,
                                                 (float*)d_out);
}

// Round 5
// 983.317 us; speedup vs baseline: 1.2058x; 1.2058x over previous
//
#include <hip/hip_runtime.h>

#define N_NODES 25000
#define E_EDGES 400000
#define KM 200     // message channels
#define RS 224     // fused row stride (floats): 200 A/B + up to 20 x + pad (896 B)

// ---------------- sort-by-dst (CSR build) ----------------

__global__ void hist_kernel(const int* __restrict__ edges, int* __restrict__ hist) {
  int e = blockIdx.x * blockDim.x + threadIdx.x;
  if (e < E_EDGES) atomicAdd(&hist[edges[E_EDGES + e]], 1);
}

__global__ void scan_kernel(const int* __restrict__ hist, int* __restrict__ off,
                            int* __restrict__ cursor) {
  __shared__ int sums[1024];
  const int CH = (N_NODES + 1023) / 1024;  // 25
  int tid = threadIdx.x;
  int base = tid * CH;
  int s = 0;
  for (int i = 0; i < CH; i++) {
    int idx = base + i;
    if (idx < N_NODES) s += hist[idx];
  }
  sums[tid] = s;
  __syncthreads();
  for (int d = 1; d < 1024; d <<= 1) {
    int v = (tid >= d) ? sums[tid - d] : 0;
    __syncthreads();
    sums[tid] += v;
    __syncthreads();
  }
  int run = (tid == 0) ? 0 : sums[tid - 1];
  for (int i = 0; i < CH; i++) {
    int idx = base + i;
    if (idx < N_NODES) {
      off[idx] = run;
      cursor[idx] = run;
      run += hist[idx];
    }
  }
  if (tid == 1023) off[N_NODES] = run;  // == E
}

__global__ void scatter_kernel(const int* __restrict__ edges, int* __restrict__ cursor,
                               int* __restrict__ srcS, int* __restrict__ dstS) {
  int e = blockIdx.x * blockDim.x + threadIdx.x;
  if (e < E_EDGES) {
    int s = edges[e];
    int d = edges[E_EDGES + e];
    int pos = atomicAdd(&cursor[d], 1);
    srcS[pos] = s;
    dstS[pos] = d;
  }
}

// ---------------- per-layer kernels ----------------

// Node prep: xv = relu?(xin)
//   A2[n] = [ xv@Wm1_top + bm1 (200) | xv (CIN) | pad ]   (stride RS floats)
//   B2[n] = [ xv@Wm1_bot       (200) | xv (CIN) | pad ]
//   xr[n][c] = xv  (compact copy for aggfin)
template <int CIN>
__global__ void prep_kernel(const float* __restrict__ xin, int do_relu,
                            const float* __restrict__ Wm1, const float* __restrict__ bm1,
                            float* __restrict__ A2, float* __restrict__ B2,
                            float* __restrict__ xr) {
  const int NT = 8;
  int k = threadIdx.x;  // 0..255
  float wa[CIN], wb[CIN];
  float bm = 0.f;
  if (k < KM) {
    bm = bm1[k];
#pragma unroll
    for (int c = 0; c < CIN; c++) {
      wa[c] = Wm1[c * KM + k];
      wb[c] = Wm1[(CIN + c) * KM + k];
    }
  }
  int n0 = blockIdx.x * NT;
  for (int i = 0; i < NT; i++) {
    int n = n0 + i;
    float xv[CIN];
#pragma unroll
    for (int c = 0; c < CIN; c++) {
      float v = xin[n * CIN + c];
      xv[c] = do_relu ? fmaxf(v, 0.f) : v;
    }
    size_t row = (size_t)n * RS;
    if (k < CIN) {
      xr[n * CIN + k] = xv[k];
      A2[row + KM + k] = xv[k];
      B2[row + KM + k] = xv[k];
    }
    if (k < KM) {
      float a = bm, b = 0.f;
#pragma unroll
      for (int c = 0; c < CIN; c++) {
        a += xv[c] * wa[c];
        b += xv[c] * wb[c];
      }
      A2[row + k] = a;
      B2[row + k] = b;
    }
  }
}

// Edge kernel: TWO independent (dst-sorted) edges per thread (e, e+E/2) for
// memory-level parallelism; R1-style float4 k-loop; gd[c][e] coalesced stores.
template <int CIN>
__global__ void __launch_bounds__(256) edge_kernel(
    const int* __restrict__ srcS, const int* __restrict__ dstS,
    const float* __restrict__ A2, const float* __restrict__ B2,
    const float* __restrict__ Wm2, const float* __restrict__ bm2,
    float* __restrict__ gd) {
  const int HALF = E_EDGES / 2;  // 200000
  int t = blockIdx.x * 256 + threadIdx.x;
  if (t >= HALF) return;
  int eA = t;
  int eB = t + HALF;
  int srcA = srcS[eA], dstA = dstS[eA];
  int srcB = srcS[eB], dstB = dstS[eB];
  const float* ArA = A2 + (size_t)dstA * RS;
  const float* BrA = B2 + (size_t)srcA * RS;
  const float* ArB = A2 + (size_t)dstB * RS;
  const float* BrB = B2 + (size_t)srcB * RS;
  float gateA[CIN], gateB[CIN];
#pragma unroll
  for (int c = 0; c < CIN; c++) {
    float b = bm2[c];
    gateA[c] = b;
    gateB[c] = b;
  }
#pragma unroll 2
  for (int k = 0; k < KM; k += 4) {
    float4 a0 = *(const float4*)(ArA + k);
    float4 b0 = *(const float4*)(BrA + k);
    float4 a1 = *(const float4*)(ArB + k);
    float4 b1 = *(const float4*)(BrB + k);
    float hA0 = fmaxf(a0.x + b0.x, 0.f);
    float hA1 = fmaxf(a0.y + b0.y, 0.f);
    float hA2 = fmaxf(a0.z + b0.z, 0.f);
    float hA3 = fmaxf(a0.w + b0.w, 0.f);
    float hB0 = fmaxf(a1.x + b1.x, 0.f);
    float hB1 = fmaxf(a1.y + b1.y, 0.f);
    float hB2 = fmaxf(a1.z + b1.z, 0.f);
    float hB3 = fmaxf(a1.w + b1.w, 0.f);
#pragma unroll
    for (int c = 0; c < CIN; c++) {
      float w0 = Wm2[(k + 0) * CIN + c];
      float w1 = Wm2[(k + 1) * CIN + c];
      float w2 = Wm2[(k + 2) * CIN + c];
      float w3 = Wm2[(k + 3) * CIN + c];
      gateA[c] += hA0 * w0 + hA1 * w1 + hA2 * w2 + hA3 * w3;
      gateB[c] += hB0 * w0 + hB1 * w1 + hB2 * w2 + hB3 * w3;
    }
  }
  // x-diff tails (same rows, L1-hot) + coalesced stores
  if constexpr (CIN % 4 == 0) {
#pragma unroll
    for (int q = 0; q < CIN / 4; q++) {
      float4 xaA = *(const float4*)(ArA + KM + 4 * q);
      float4 xbA = *(const float4*)(BrA + KM + 4 * q);
      float4 xaB = *(const float4*)(ArB + KM + 4 * q);
      float4 xbB = *(const float4*)(BrB + KM + 4 * q);
      float xdA[4] = {xaA.x - xbA.x, xaA.y - xbA.y, xaA.z - xbA.z, xaA.w - xbA.w};
      float xdB[4] = {xaB.x - xbB.x, xaB.y - xbB.y, xaB.z - xbB.z, xaB.w - xbB.w};
#pragma unroll
      for (int j = 0; j < 4; j++) {
        int c = 4 * q + j;
        gd[(size_t)c * E_EDGES + eA] = gateA[c] * xdA[j];
        gd[(size_t)c * E_EDGES + eB] = gateB[c] * xdB[j];
      }
    }
  } else {
#pragma unroll
    for (int c = 0; c < CIN; c++) {
      gd[(size_t)c * E_EDGES + eA] = gateA[c] * (ArA[KM + c] - BrA[KM + c]);
      gd[(size_t)c * E_EDGES + eB] = gateB[c] * (ArB[KM + c] - BrB[KM + c]);
    }
  }
}

// aggfin (CIN=1): thread per node; segment-sum gd[0][...] then 20 outputs.
__global__ void aggfin_1_20(const float* __restrict__ gd, const int* __restrict__ off,
                            const float* __restrict__ xr,
                            const float* __restrict__ W1, const float* __restrict__ b1,
                            const float* __restrict__ W2, const float* __restrict__ b2,
                            float* __restrict__ out) {
  int n = blockIdx.x * blockDim.x + threadIdx.x;
  if (n >= N_NODES) return;
  int s = off[n];
  int t = off[n + 1];
  float v = 0.f;
  for (int e = s; e < t; e++) v += gd[e];
  float x = xr[n];
  float deg = (float)(t - s);
#pragma unroll
  for (int o = 0; o < 20; o++) {
    out[n * 20 + o] = b1[o] + deg * b2[o] + v * W2[o] + x * W1[o];
  }
}

// aggfin (CIN=20): 12 nodes/block, thread (g,c): segment-sum channel c of node
// n(g) into LDS, then thread (g,o) computes out[n][o] via 20x(2 FMA).
template <int COUT>
__global__ void __launch_bounds__(256) aggfin_20(
    const float* __restrict__ gd, const int* __restrict__ off,
    const float* __restrict__ xr,
    const float* __restrict__ W1, const float* __restrict__ b1,
    const float* __restrict__ W2, const float* __restrict__ b2,
    float* __restrict__ out) {
  __shared__ float lag[12][21];
  __shared__ float lx[12][21];
  int g = threadIdx.x / 20;
  int c = threadIdx.x - g * 20;
  int n = blockIdx.x * 12 + g;
  bool act = (g < 12) && (n < N_NODES);
  int s = 0, t = 0;
  if (act) {
    s = off[n];
    t = off[n + 1];
    const float* row = gd + (size_t)c * E_EDGES;
    float v = 0.f;
    for (int e = s; e < t; e++) v += row[e];
    lag[g][c] = v;
    lx[g][c] = xr[n * 20 + c];
  }
  __syncthreads();
  if (act && c < COUT) {
    float deg = (float)(t - s);
    float v = b1[c] + deg * b2[c];
#pragma unroll
    for (int cc = 0; cc < 20; cc++) {
      v += lag[g][cc] * W2[cc * COUT + c] + lx[g][cc] * W1[cc * COUT + c];
    }
    out[(size_t)n * COUT + c] = v;
  }
}

// ---------------- launch ----------------

extern "C" void kernel_launch(void* const* d_in, const int* in_sizes, int n_in,
                              void* d_out, int out_size, void* d_ws, size_t ws_size,
                              hipStream_t stream) {
  const float* features = (const float*)d_in[0];
  const int* edges = (const int*)d_in[1];
  // d_in[2] = weights (unused by reference)

  const float *dW1 = (const float*)d_in[3], *db1 = (const float*)d_in[4],
              *dWm1 = (const float*)d_in[5], *dbm1 = (const float*)d_in[6],
              *dWm2 = (const float*)d_in[7], *dbm2 = (const float*)d_in[8],
              *dW2 = (const float*)d_in[9], *db2 = (const float*)d_in[10];
  const float *hW1 = (const float*)d_in[11], *hb1 = (const float*)d_in[12],
              *hWm1 = (const float*)d_in[13], *hbm1 = (const float*)d_in[14],
              *hWm2 = (const float*)d_in[15], *hbm2 = (const float*)d_in[16],
              *hW2 = (const float*)d_in[17], *hb2 = (const float*)d_in[18];
  const float *oW1 = (const float*)d_in[19], *ob1 = (const float*)d_in[20],
              *oWm1 = (const float*)d_in[21], *obm1 = (const float*)d_in[22],
              *oWm2 = (const float*)d_in[23], *obm2 = (const float*)d_in[24],
              *oW2 = (const float*)d_in[25], *ob2 = (const float*)d_in[26];

  // workspace layout (float units)
  float* fws = (float*)d_ws;
  size_t o = 0;
  float* A2 = fws + o;   o += (size_t)N_NODES * RS;   // 5.6M
  float* B2 = fws + o;   o += (size_t)N_NODES * RS;   // 5.6M
  float* gd = fws + o;   o += (size_t)20 * E_EDGES;   // 8.0M
  float* xr = fws + o;   o += (size_t)N_NODES * 20;
  float* acc1 = fws + o; o += (size_t)N_NODES * 20;
  float* acc2 = fws + o; o += (size_t)N_NODES * 20;
  int* ip = (int*)(fws + o);
  int* hist = ip;   ip += N_NODES;
  int* off = ip;    ip += N_NODES + 4;
  int* cursor = ip; ip += N_NODES;
  int* srcS = ip;   ip += E_EDGES;
  int* dstS = ip;   ip += E_EDGES;

  const int B256 = 256;
  const int EDGE_G = (E_EDGES / 2 + B256 - 1) / B256;  // 782 (2 edges/thread)
  const int NODE_G = (N_NODES + B256 - 1) / B256;
  const int PREP_G = N_NODES / 8;  // 3125, exact
  const int AGGF_G = (N_NODES + 11) / 12;  // 2084

  // build dst-sorted edge list + CSR offsets (recomputed every launch)
  hipMemsetAsync(hist, 0, N_NODES * sizeof(int), stream);
  hist_kernel<<<(E_EDGES + B256 - 1) / B256, B256, 0, stream>>>(edges, hist);
  scan_kernel<<<1, 1024, 0, stream>>>(hist, off, cursor);
  scatter_kernel<<<(E_EDGES + B256 - 1) / B256, B256, 0, stream>>>(edges, cursor, srcS, dstS);

  // layer d: 1 -> 20
  prep_kernel<1><<<PREP_G, B256, 0, stream>>>(features, 0, dWm1, dbm1, A2, B2, xr);
  edge_kernel<1><<<EDGE_G, B256, 0, stream>>>(srcS, dstS, A2, B2, dWm2, dbm2, gd);
  aggfin_1_20<<<NODE_G, B256, 0, stream>>>(gd, off, xr, dW1, db1, dW2, db2, acc1);

  // 3 hidden layers: 20 -> 20 (relu applied to input inside prep)
  float* cur = acc1;
  float* nxt = acc2;
  for (int i = 0; i < 3; i++) {
    prep_kernel<20><<<PREP_G, B256, 0, stream>>>(cur, 1, hWm1, hbm1, A2, B2, xr);
    edge_kernel<20><<<EDGE_G, B256, 0, stream>>>(srcS, dstS, A2, B2, hWm2, hbm2, gd);
    aggfin_20<20><<<AGGF_G, B256, 0, stream>>>(gd, off, xr, hW1, hb1, hW2, hb2, nxt);
    float* tmp = cur; cur = nxt; nxt = tmp;
  }

  // output layer: 20 -> 1 (no trailing relu)
  prep_kernel<20><<<PREP_G, B256, 0, stream>>>(cur, 1, oWm1, obm1, A2, B2, xr);
  edge_kernel<20><<<EDGE_G, B256, 0, stream>>>(srcS, dstS, A2, B2, oWm2, obm2, gd);
  aggfin_20<1><<<AGGF_G, B256, 0, stream>>>(gd, off, xr, oW1, ob1, oW2, ob2,
                                            (float*)d_out);
}